// Round 10
// baseline (37.546 us; speedup 1.0000x reference)
//
#include <hip/hip_runtime.h>
#include <hip/hip_bf16.h>

#define N_TOK 65536
#define DIM 64
#define K_CODES 1024

typedef float f32x4 __attribute__((ext_vector_type(4)));
typedef int   i32x2 __attribute__((ext_vector_type(2)));
typedef unsigned uintx4 __attribute__((ext_vector_type(4)));

// pack 4 f32 -> 4 OCP e4m3 bytes
static __device__ __forceinline__ int pk_fp8x4(float a, float b, float c, float d) {
    int v = __builtin_amdgcn_cvt_pk_fp8_f32(a, b, 0, false);
    v = __builtin_amdgcn_cvt_pk_fp8_f32(c, d, v, true);
    return v;
}
static __device__ __forceinline__ long pk_fp8x8(f32x4 x, f32x4 y) {
    i32x2 t;
    t[0] = pk_fp8x4(x[0], x[1], x[2], x[3]);
    t[1] = pk_fp8x4(y[0], y[1], y[2], y[3]);
    return __builtin_bit_cast(long, t);
}

// LDS swizzle for the 64 KB fp8 B-tile (XOR addr bits [9:7] into [6:4]);
// applied to both staging ds_write and K-loop ds_read.
static __device__ __forceinline__ int swz8(int byte_off) {
    return byte_off ^ (((byte_off >> 7) & 7) << 4);
}

// DPP row_shr reductions on the VALU pipe. row_shr:n = lane i reads lane i-n
// (accumulates toward HIGHER lanes; canonical GCN reduction reads lane 63).
// bound_ctrl=true zero-fills below-row reads (identity for + and unsigned max).
template <int N>
static __device__ __forceinline__ float dpp_shr_addf(float x) {
    int t = __builtin_amdgcn_update_dpp(0, __builtin_bit_cast(int, x),
                                        0x110 + N, 0xF, 0xF, true);
    return x + __builtin_bit_cast(float, t);
}
template <int N>
static __device__ __forceinline__ unsigned dpp_shr_maxu(unsigned x) {
    unsigned t = (unsigned)__builtin_amdgcn_update_dpp(0, (int)x,
                                                       0x110 + N, 0xF, 0xF, true);
    return x > t ? x : t;
}

// Main: 256 blocks x 1024 threads (16 waves, 1 block/CU). Block covers 256 rows.
// Wave (rg = w>>2, h = w&3): rows rg*64..+63 (4 m-tiles) vs code quarter h.
// B-tile fp8 (emb*2048, e4m3) in LDS; frag f = tile*2 + s at swz8(f*512+lane*8).
// Code norms transposed in lds_ct[c*68 + tile] (pad 68 -> conflict-free b128),
// preloaded to 16 VGPRs/lane before the K-loop. Argmin maximizes
// tv = <l,2048e> + 2048*(4 - ||e||^2/2) > 0, tile idx packed in low 4 mantissa
// bits under max; 16-lane reduce via DPP row_shr max (result lands at c==15).
// Loss row term = 8 - tv/1024 + ||l||^2. Per-block partial -> partials[].
__global__ __launch_bounds__(1024, 4) void vq_main(const float* __restrict__ lat,
                                                   const float* __restrict__ emb,
                                                   float* __restrict__ out,
                                                   float* __restrict__ partials) {
    __shared__ __align__(16) char lds_b[65536];       // 64 KB fp8 B-tile
    __shared__ __align__(16) float lds_ct[16 * 68];   // transposed norms, padded
    __shared__ __align__(16) unsigned lds_comb[1024]; // [row 0..255][h]
    __shared__ int lds_code[256];
    __shared__ float lds_lnp[16];
    __shared__ float lds_rl[4];

    const int tid  = threadIdx.x;
    const int lane = tid & 63;
    const int wave = tid >> 6;
    const int rg = wave >> 2;
    const int h  = wave & 3;
    const int c = lane & 15;
    const int g = lane >> 4;
    const int wrow0 = blockIdx.x * 256 + rg * 64;

    // A-fragments (4 m-tiles of 16 rows) as fp8 + exact f32 ||l||^2 partial
    long a[4][2];
    float lnp = 0.f;
#pragma unroll
    for (int m = 0; m < 4; ++m) {
        const f32x4* rp4 = reinterpret_cast<const f32x4*>(lat + (size_t)(wrow0 + m * 16 + c) * DIM);
        f32x4 p0 = rp4[g * 2], p1 = rp4[g * 2 + 1];
        f32x4 p2 = rp4[8 + g * 2], p3 = rp4[8 + g * 2 + 1];
#pragma unroll
        for (int j = 0; j < 4; ++j) {
            lnp = fmaf(p0[j], p0[j], lnp); lnp = fmaf(p1[j], p1[j], lnp);
            lnp = fmaf(p2[j], p2[j], lnp); lnp = fmaf(p3[j], p3[j], lnp);
        }
        a[m][0] = pk_fp8x8(p0, p1);
        a[m][1] = pk_fp8x8(p2, p3);
    }
    // full-wave sum: 4 DPP steps within rows of 16 (sum at lane 15 of each row),
    // then 2 cross-row xor steps -> total valid at lane 63
    lnp = dpp_shr_addf<1>(lnp); lnp = dpp_shr_addf<2>(lnp);
    lnp = dpp_shr_addf<4>(lnp); lnp = dpp_shr_addf<8>(lnp);
    lnp += __shfl_xor(lnp, 16, 64);
    lnp += __shfl_xor(lnp, 32, 64);
    if (lane == 63) lds_lnp[wave] = lnp;   // rows counted once via h==0 waves

    // Stage + convert codebook (scaled x2048 into e4m3); norms via DPP row_shr
    // (8-group sum lands at the HIGH lane: (u&7)==7; code = u>>3 same across group).
#pragma unroll
    for (int i = 0; i < 8; ++i) {
        const int u = i * 1024 + tid;            // 0..8191
        const int code = u >> 3, d0 = (u & 7) * 8;
        f32x4 q0 = *reinterpret_cast<const f32x4*>(emb + (size_t)u * 8);
        f32x4 q1 = *reinterpret_cast<const f32x4*>(emb + (size_t)u * 8 + 4);
        float ns = 0.f;
#pragma unroll
        for (int j = 0; j < 4; ++j) { ns = fmaf(q0[j], q0[j], ns); ns = fmaf(q1[j], q1[j], ns); }
        ns = dpp_shr_addf<1>(ns);
        ns = dpp_shr_addf<2>(ns);
        ns = dpp_shr_addf<4>(ns);
        i32x2 v;
        v[0] = pk_fp8x4(q0[0] * 2048.f, q0[1] * 2048.f, q0[2] * 2048.f, q0[3] * 2048.f);
        v[1] = pk_fp8x4(q1[0] * 2048.f, q1[1] * 2048.f, q1[2] * 2048.f, q1[3] * 2048.f);
        const int f  = (code >> 4) * 2 + (d0 >> 5);
        const int lt = (code & 15) + ((d0 & 31) >> 3) * 16;
        *reinterpret_cast<i32x2*>(lds_b + swz8(f * 512 + lt * 8)) = v;
        if ((u & 7) == 7)
            lds_ct[(code & 15) * 68 + (code >> 4)] = 8192.0f - 1024.0f * ns;
    }

    unsigned pm[4][4];
#pragma unroll
    for (int m = 0; m < 4; ++m)
#pragma unroll
        for (int j = 0; j < 4; ++j) pm[m][j] = 0u;

    const int bb = h * 16384 + lane * 8;
    __syncthreads();

    // preload this lane's 16 code-norm constants (4 conflict-free ds_read_b128)
    f32x4 cvreg[4];
    {
        const f32x4* ctb = reinterpret_cast<const f32x4*>(&lds_ct[c * 68 + h * 16]);
        cvreg[0] = ctb[0]; cvreg[1] = ctb[1]; cvreg[2] = ctb[2]; cvreg[3] = ctb[3];
    }

#pragma unroll
    for (int ti = 0; ti < 16; ++ti) {
        long b0 = *reinterpret_cast<const long*>(lds_b + swz8(bb + ti * 1024));
        long b1 = *reinterpret_cast<const long*>(lds_b + swz8(bb + ti * 1024 + 512));
        const float cv = cvreg[ti >> 2][ti & 3];
        f32x4 cvv = {cv, cv, cv, cv};
        const unsigned ib = 15u - (unsigned)ti;
#pragma unroll
        for (int m = 0; m < 4; ++m) {
            f32x4 acc = __builtin_amdgcn_mfma_f32_16x16x32_fp8_fp8(a[m][0], b0, cvv, 0, 0, 0);
            acc = __builtin_amdgcn_mfma_f32_16x16x32_fp8_fp8(a[m][1], b1, acc, 0, 0, 0);
#pragma unroll
            for (int j = 0; j < 4; ++j) {
                unsigned ub = __builtin_bit_cast(unsigned, acc[j]);
                unsigned pv = (ub & 0xFFFFFFF0u) | ib;
                pm[m][j] = pm[m][j] < pv ? pv : pm[m][j];
            }
        }
    }

    // repack with 10-bit global code, then 16-lane max via DPP (result at c==15)
#pragma unroll
    for (int m = 0; m < 4; ++m) {
#pragma unroll
        for (int j = 0; j < 4; ++j) {
            unsigned v = pm[m][j];
            unsigned gcode = ((unsigned)h * 16u + (15u - (v & 15u))) * 16u + (unsigned)c;
            v = (v & 0xFFFFFC00u) | (1023u - gcode);
            v = dpp_shr_maxu<1>(v);
            v = dpp_shr_maxu<2>(v);
            v = dpp_shr_maxu<4>(v);
            v = dpp_shr_maxu<8>(v);
            pm[m][j] = v;
        }
    }
    if (c == 15) {
#pragma unroll
        for (int m = 0; m < 4; ++m)
#pragma unroll
            for (int j = 0; j < 4; ++j) {
                const int row = rg * 64 + m * 16 + g * 4 + j;   // block-local
                lds_comb[row * 4 + h] = pm[m][j];
            }
    }
    __syncthreads();

    // combine across h (256 rows); emit winner code + per-row loss term
    if (tid < 256) {
        uintx4 cm = *reinterpret_cast<const uintx4*>(&lds_comb[tid * 4]);
        unsigned v0 = cm[0] > cm[1] ? cm[0] : cm[1];
        unsigned v1 = cm[2] > cm[3] ? cm[2] : cm[3];
        unsigned v = v0 > v1 ? v0 : v1;
        lds_code[tid] = (int)(1023u - (v & 1023u));
        float tv = __builtin_bit_cast(float, v & 0xFFFFFC00u);
        float rl = fmaf(-1.0f / 1024.0f, tv, 8.0f);    // 8 - 2*tv_unscaled
        rl = dpp_shr_addf<1>(rl); rl = dpp_shr_addf<2>(rl);
        rl = dpp_shr_addf<4>(rl); rl = dpp_shr_addf<8>(rl);
        rl += __shfl_xor(rl, 16, 64);
        rl += __shfl_xor(rl, 32, 64);
        if (lane == 63) lds_rl[wave] = rl;
    }
    __syncthreads();

    // coalesced output gather: 256 rows x 64 f32 dims as 16B chunks
#pragma unroll
    for (int it = 0; it < 4; ++it) {
        const int cidx = it * 1024 + tid;
        const int row = cidx >> 4, seg = cidx & 15;
        const int gc = lds_code[row];
        reinterpret_cast<f32x4*>(out)[(size_t)(blockIdx.x * 256 + row) * 16 + seg] =
            reinterpret_cast<const f32x4*>(emb)[(size_t)gc * 16 + seg];
    }
    if (tid == 0) {
        partials[blockIdx.x] = lds_rl[0] + lds_rl[1] + lds_rl[2] + lds_rl[3]
                             + lds_lnp[0] + lds_lnp[4] + lds_lnp[8] + lds_lnp[12];
    }
}

// one wave: sum 256 per-block partials (fixed order), scale, write loss scalar
__global__ __launch_bounds__(64) void vq_finalize(const float* __restrict__ partials,
                                                  float* __restrict__ loss_out) {
    const int lane = threadIdx.x;
    f32x4 p4 = reinterpret_cast<const f32x4*>(partials)[lane];
    float p = (p4[0] + p4[1]) + (p4[2] + p4[3]);
#pragma unroll
    for (int off = 1; off < 64; off <<= 1) p += __shfl_xor(p, off, 64);
    if (lane == 0) loss_out[0] = p * (1.25f / 4194304.f);
}

extern "C" void kernel_launch(void* const* d_in, const int* in_sizes, int n_in,
                              void* d_out, int out_size, void* d_ws, size_t ws_size,
                              hipStream_t stream) {
    const float* lat = (const float*)d_in[0];
    const float* emb = (const float*)d_in[1];
    float* out = (float*)d_out;
    float* partials = (float*)d_ws;

    vq_main<<<256, 1024, 0, stream>>>(lat, emb, out, partials);
    vq_finalize<<<1, 64, 0, stream>>>(partials, out + (size_t)N_TOK * DIM);
}

// Round 11
// 33.583 us; speedup vs baseline: 1.1180x; 1.1180x over previous
//
#include <hip/hip_runtime.h>
#include <hip/hip_bf16.h>

#define N_TOK 65536
#define DIM 64
#define K_CODES 1024

typedef float f32x4 __attribute__((ext_vector_type(4)));
typedef int   i32x2 __attribute__((ext_vector_type(2)));

// pack 4 f32 -> 4 OCP e4m3 bytes
static __device__ __forceinline__ int pk_fp8x4(float a, float b, float c, float d) {
    int v = __builtin_amdgcn_cvt_pk_fp8_f32(a, b, 0, false);
    v = __builtin_amdgcn_cvt_pk_fp8_f32(c, d, v, true);
    return v;
}
static __device__ __forceinline__ long pk_fp8x8(f32x4 x, f32x4 y) {
    i32x2 t;
    t[0] = pk_fp8x4(x[0], x[1], x[2], x[3]);
    t[1] = pk_fp8x4(y[0], y[1], y[2], y[3]);
    return __builtin_bit_cast(long, t);
}

// DPP row_shr reductions (VALU pipe). row_shr:n = lane i reads lane i-n;
// totals accumulate toward HIGHER lanes (group sum at lane 15 of each row16,
// wave total at lane 63 after the two xor steps). bound_ctrl zero-fills.
template <int N>
static __device__ __forceinline__ float dpp_shr_addf(float x) {
    int t = __builtin_amdgcn_update_dpp(0, __builtin_bit_cast(int, x),
                                        0x110 + N, 0xF, 0xF, true);
    return x + __builtin_bit_cast(float, t);
}
template <int N>
static __device__ __forceinline__ unsigned dpp_shr_maxu(unsigned x) {
    unsigned t = (unsigned)__builtin_amdgcn_update_dpp(0, (int)x,
                                                       0x110 + N, 0xF, 0xF, true);
    return x > t ? x : t;
}

// ws layout (bytes): [0, 8192) per-wave loss partials f32[2048];
// [8192, 12288) cvec_t f32[1024]: cvec_t[(code&15)*64 + (code>>4)] =
//   2048*(4 - ||e||^2/2);  [16384, 16384+65536) fp8 B-fragments:
//   frag f = tile*2 + s holds B[k][col] = 2048*emb[tile*16 + (lane&15)]
//   [s*32 + (lane>>4)*8 + j] at byte f*512 + lane*8.
__global__ __launch_bounds__(128) void vq_prep(const float* __restrict__ emb,
                                               float* __restrict__ cvec_t,
                                               char* __restrict__ bfrag) {
    const int u = blockIdx.x * 128 + threadIdx.x;   // 0..8191
    const int code = u >> 3, d0 = (u & 7) * 8;
    f32x4 q0 = *reinterpret_cast<const f32x4*>(emb + (size_t)u * 8);
    f32x4 q1 = *reinterpret_cast<const f32x4*>(emb + (size_t)u * 8 + 4);
    float ns = 0.f;
#pragma unroll
    for (int j = 0; j < 4; ++j) { ns = fmaf(q0[j], q0[j], ns); ns = fmaf(q1[j], q1[j], ns); }
    ns = dpp_shr_addf<1>(ns);
    ns = dpp_shr_addf<2>(ns);
    ns = dpp_shr_addf<4>(ns);   // 8-group sum at (u&7)==7
    i32x2 v;
    v[0] = pk_fp8x4(q0[0] * 2048.f, q0[1] * 2048.f, q0[2] * 2048.f, q0[3] * 2048.f);
    v[1] = pk_fp8x4(q1[0] * 2048.f, q1[1] * 2048.f, q1[2] * 2048.f, q1[3] * 2048.f);
    const int f  = (code >> 4) * 2 + (d0 >> 5);
    const int lt = (code & 15) + ((d0 & 31) >> 3) * 16;
    *reinterpret_cast<i32x2*>(bfrag + f * 512 + lt * 8) = v;
    if ((u & 7) == 7)
        cvec_t[(code & 15) * 64 + (code >> 4)] = 8192.0f - 1024.0f * ns;
}

// Main: 512 blocks x 256 threads; each wave INDEPENDENT (no __syncthreads).
// Wave owns 32 rows (2 m-tiles) x all 1024 codes; B-fragments streamed
// straight from L2 (coalesced 512 B / wave-instruction). Argmin maximizes
// tv = <l,2048e> + 2048*(4 - ||e||^2/2) > 0, 6 tile-idx bits packed in the
// low mantissa under max; 16-lane DPP max -> winner at c==15. Loss row term
// = 8 - tv/1024 + ||l||^2; per-wave partial -> partials[gwave].
__global__ __launch_bounds__(256) void vq_main(const float* __restrict__ lat,
                                               const float* __restrict__ emb,
                                               const float* __restrict__ cvec_t,
                                               const char* __restrict__ bfrag,
                                               float* __restrict__ out,
                                               float* __restrict__ partials) {
    __shared__ int lds_code[128];   // 32 per wave, wave-private region

    const int tid  = threadIdx.x;
    const int lane = tid & 63;
    const int wave = tid >> 6;
    const int c = lane & 15;
    const int g = lane >> 4;
    const int gwave = blockIdx.x * 4 + wave;
    const int wrow0 = gwave * 32;

    // A-fragments (2 m-tiles of 16 rows) as fp8 + exact f32 ||l||^2 partial
    long a[2][2];
    float lnp = 0.f;
#pragma unroll
    for (int m = 0; m < 2; ++m) {
        const f32x4* rp4 = reinterpret_cast<const f32x4*>(lat + (size_t)(wrow0 + m * 16 + c) * DIM);
        f32x4 p0 = rp4[g * 2], p1 = rp4[g * 2 + 1];
        f32x4 p2 = rp4[8 + g * 2], p3 = rp4[8 + g * 2 + 1];
#pragma unroll
        for (int j = 0; j < 4; ++j) {
            lnp = fmaf(p0[j], p0[j], lnp); lnp = fmaf(p1[j], p1[j], lnp);
            lnp = fmaf(p2[j], p2[j], lnp); lnp = fmaf(p3[j], p3[j], lnp);
        }
        a[m][0] = pk_fp8x8(p0, p1);
        a[m][1] = pk_fp8x8(p2, p3);
    }
    lnp = dpp_shr_addf<1>(lnp); lnp = dpp_shr_addf<2>(lnp);
    lnp = dpp_shr_addf<4>(lnp); lnp = dpp_shr_addf<8>(lnp);
    lnp += __shfl_xor(lnp, 16, 64);
    lnp += __shfl_xor(lnp, 32, 64);   // wave total valid at lane 63

    unsigned pm[2][4];
#pragma unroll
    for (int m = 0; m < 2; ++m)
#pragma unroll
        for (int j = 0; j < 4; ++j) pm[m][j] = 0u;

    const char* bb = bfrag + lane * 8;
    const f32x4* cvp = reinterpret_cast<const f32x4*>(cvec_t + c * 64);

#pragma unroll 2
    for (int t4 = 0; t4 < 16; ++t4) {
        const f32x4 cv4 = cvp[t4];   // norms for tiles t4*4..+3 (L1-hot)
#pragma unroll
        for (int tt = 0; tt < 4; ++tt) {
            const int ti = t4 * 4 + tt;
            long b0 = *reinterpret_cast<const long*>(bb + ti * 1024);
            long b1 = *reinterpret_cast<const long*>(bb + ti * 1024 + 512);
            const float cv = cv4[tt];
            f32x4 cvv = {cv, cv, cv, cv};
            const unsigned ib = 63u - (unsigned)ti;
#pragma unroll
            for (int m = 0; m < 2; ++m) {
                f32x4 acc = __builtin_amdgcn_mfma_f32_16x16x32_fp8_fp8(a[m][0], b0, cvv, 0, 0, 0);
                acc = __builtin_amdgcn_mfma_f32_16x16x32_fp8_fp8(a[m][1], b1, acc, 0, 0, 0);
#pragma unroll
                for (int j = 0; j < 4; ++j) {
                    unsigned ub = __builtin_bit_cast(unsigned, acc[j]);
                    unsigned pv = (ub & 0xFFFFFFC0u) | ib;
                    pm[m][j] = pm[m][j] < pv ? pv : pm[m][j];
                }
            }
        }
    }

    // repack with 10-bit global code, 16-lane DPP max (winner at c==15),
    // write codes to wave-private LDS, accumulate loss terms at c==15
    float rls = 0.f;
#pragma unroll
    for (int m = 0; m < 2; ++m) {
#pragma unroll
        for (int j = 0; j < 4; ++j) {
            unsigned v = pm[m][j];
            unsigned gcode = ((63u - (v & 63u)) << 4) | (unsigned)c;
            v = (v & 0xFFFFFC00u) | (1023u - gcode);
            v = dpp_shr_maxu<1>(v);
            v = dpp_shr_maxu<2>(v);
            v = dpp_shr_maxu<4>(v);
            v = dpp_shr_maxu<8>(v);
            if (c == 15) {
                lds_code[wave * 32 + m * 16 + g * 4 + j] = (int)(1023u - (v & 1023u));
                float tv = __builtin_bit_cast(float, v & 0xFFFFFC00u);
                rls += fmaf(-1.0f / 1024.0f, tv, 8.0f);   // 8 - 2*dot_min-ish
            }
        }
    }
    rls = dpp_shr_addf<1>(rls); rls = dpp_shr_addf<2>(rls);
    rls = dpp_shr_addf<4>(rls); rls = dpp_shr_addf<8>(rls);
    rls += __shfl_xor(rls, 16, 64);
    rls += __shfl_xor(rls, 32, 64);
    if (lane == 63) partials[gwave] = rls + lnp;

    // wave-private gather: 32 rows x 16 segs of 16 B; 16 lanes cover one row
#pragma unroll
    for (int i = 0; i < 8; ++i) {
        const int row = i * 4 + g;
        const int gc = lds_code[wave * 32 + row];
        reinterpret_cast<f32x4*>(out)[(size_t)(wrow0 + row) * 16 + c] =
            reinterpret_cast<const f32x4*>(emb)[(size_t)gc * 16 + c];
    }
}

// one wave: sum 2048 per-wave partials in fixed order, scale, write scalar
__global__ __launch_bounds__(64) void vq_finalize(const float* __restrict__ partials,
                                                  float* __restrict__ loss_out) {
    const int lane = threadIdx.x;
    const f32x4* p4 = reinterpret_cast<const f32x4*>(partials);
    float p = 0.f;
#pragma unroll
    for (int k = 0; k < 8; ++k) {
        f32x4 q = p4[lane * 8 + k];
        p += ((q[0] + q[1]) + (q[2] + q[3]));
    }
#pragma unroll
    for (int off = 1; off < 64; off <<= 1) p += __shfl_xor(p, off, 64);
    if (lane == 0) loss_out[0] = p * (1.25f / 4194304.f);
}

extern "C" void kernel_launch(void* const* d_in, const int* in_sizes, int n_in,
                              void* d_out, int out_size, void* d_ws, size_t ws_size,
                              hipStream_t stream) {
    const float* lat = (const float*)d_in[0];
    const float* emb = (const float*)d_in[1];
    float* out = (float*)d_out;
    float* partials = (float*)d_ws;                      // 8 KB
    float* cvec_t = (float*)((char*)d_ws + 8192);        // 4 KB
    char*  bfrag  = (char*)d_ws + 16384;                 // 64 KB

    vq_prep<<<64, 128, 0, stream>>>(emb, cvec_t, bfrag);
    vq_main<<<512, 256, 0, stream>>>(lat, emb, cvec_t, bfrag, out, partials);
    vq_finalize<<<1, 64, 0, stream>>>(partials, out + (size_t)N_TOK * DIM);
}